// Round 1
// baseline (1346.097 us; speedup 1.0000x reference)
//
#include <hip/hip_runtime.h>
#include <math.h>

#define E_TOT   262144
#define LDIM    128
#define KC      44
#define NCHUNK  3
#define TILE    32
#define PITCH   132
#define MIN_VARF 0.001f
#define INV_SQRT2F   0.70710678118654752f
#define INV_SQRT2PIF 0.3989422804014327f

__device__ __forceinline__ void adf_relu(float& m, float& v) {
    float vv  = fmaxf(v, 1e-6f);
    float sd  = sqrtf(vv);
    float r   = m / sd;
    float cdf = 0.5f * (1.0f + erff(r * INV_SQRT2F));
    float pdf = expf(-0.5f * r * r) * INV_SQRT2PIF;
    float mo  = m * cdf + sd * pdf;
    float vo  = (m * m + vv) * cdf + m * sd * pdf - mo * mo;
    m = mo; v = vo;
}

__device__ __forceinline__ void do_layer(
    float (&xm)[TILE][PITCH], float (&xv)[TILE][PITCH], float (&wt)[KC][PITCH],
    const float* __restrict__ Wg, const float* __restrict__ bg,
    const float* __restrict__ drop_mask, int Kfull, int gbase)
{
    const int tid = threadIdx.x;
    const int tx = tid & 15, ty = tid >> 4;
    const int e0 = ty * 2, e1 = e0 + 1;
    float am0[8], am1[8], av0[8], av1[8];
#pragma unroll
    for (int j = 0; j < 8; ++j) { am0[j] = 0.f; am1[j] = 0.f; av0[j] = 0.f; av1[j] = 0.f; }

    for (int c = 0; c < NCHUNK; ++c) {
        const int k0 = c * KC;
        __syncthreads();
        for (int idx = tid; idx < LDIM * KC; idx += 256) {
            int i  = idx / KC;
            int kk = idx - i * KC;
            int k  = k0 + kk;
            wt[kk][i] = (k < Kfull) ? Wg[i * Kfull + k] : 0.0f;
        }
        __syncthreads();
#pragma unroll 4
        for (int kk = 0; kk < KC; ++kk) {
            float a0 = xm[e0][k0 + kk];
            float a1 = xm[e1][k0 + kk];
            float s0 = xv[e0][k0 + kk];
            float s1 = xv[e1][k0 + kk];
            const float4* wp = reinterpret_cast<const float4*>(&wt[kk][tx * 8]);
            float4 wA = wp[0];
            float4 wB = wp[1];
            float w_[8] = {wA.x, wA.y, wA.z, wA.w, wB.x, wB.y, wB.z, wB.w};
#pragma unroll
            for (int j = 0; j < 8; ++j) {
                float w = w_[j];
                float w2 = w * w;
                am0[j] = fmaf(w, a0, am0[j]);
                am1[j] = fmaf(w, a1, am1[j]);
                av0[j] = fmaf(w2, s0, av0[j]);
                av1[j] = fmaf(w2, s1, av1[j]);
            }
        }
    }
    {
        float4 bA = *reinterpret_cast<const float4*>(&bg[tx * 8]);
        float4 bB = *reinterpret_cast<const float4*>(&bg[tx * 8 + 4]);
        float b_[8] = {bA.x, bA.y, bA.z, bA.w, bB.x, bB.y, bB.z, bB.w};
#pragma unroll
        for (int j = 0; j < 8; ++j) { am0[j] += b_[j]; am1[j] += b_[j]; }
    }
    if (drop_mask == nullptr) {
#pragma unroll
        for (int j = 0; j < 8; ++j) { adf_relu(am0[j], av0[j]); adf_relu(am1[j], av1[j]); }
    } else {
        const float4* dp0 = reinterpret_cast<const float4*>(&drop_mask[(size_t)(gbase + e0) * LDIM + tx * 8]);
        const float4* dp1 = reinterpret_cast<const float4*>(&drop_mask[(size_t)(gbase + e1) * LDIM + tx * 8]);
        float4 d0A = dp0[0], d0B = dp0[1];
        float4 d1A = dp1[0], d1B = dp1[1];
        float d0_[8] = {d0A.x, d0A.y, d0A.z, d0A.w, d0B.x, d0B.y, d0B.z, d0B.w};
        float d1_[8] = {d1A.x, d1A.y, d1A.z, d1A.w, d1B.x, d1B.y, d1B.z, d1B.w};
#pragma unroll
        for (int j = 0; j < 8; ++j) {
            am0[j] *= d0_[j]; av0[j] = av0[j] * d0_[j] * d0_[j] + MIN_VARF;
            am1[j] *= d1_[j]; av1[j] = av1[j] * d1_[j] * d1_[j] + MIN_VARF;
        }
    }
    __syncthreads();
    *reinterpret_cast<float4*>(&xm[e0][tx * 8])     = make_float4(am0[0], am0[1], am0[2], am0[3]);
    *reinterpret_cast<float4*>(&xm[e0][tx * 8 + 4]) = make_float4(am0[4], am0[5], am0[6], am0[7]);
    *reinterpret_cast<float4*>(&xm[e1][tx * 8])     = make_float4(am1[0], am1[1], am1[2], am1[3]);
    *reinterpret_cast<float4*>(&xm[e1][tx * 8 + 4]) = make_float4(am1[4], am1[5], am1[6], am1[7]);
    *reinterpret_cast<float4*>(&xv[e0][tx * 8])     = make_float4(av0[0], av0[1], av0[2], av0[3]);
    *reinterpret_cast<float4*>(&xv[e0][tx * 8 + 4]) = make_float4(av0[4], av0[5], av0[6], av0[7]);
    *reinterpret_cast<float4*>(&xv[e1][tx * 8])     = make_float4(av1[0], av1[1], av1[2], av1[3]);
    *reinterpret_cast<float4*>(&xv[e1][tx * 8 + 4]) = make_float4(av1[4], av1[5], av1[6], av1[7]);
}

__global__ void __launch_bounds__(256, 2)
interp_main(const float* __restrict__ pos_source,
            const float* __restrict__ pos_target,
            const float* __restrict__ latents,
            const float* __restrict__ varr,
            const float* __restrict__ drop_mask,
            const float* __restrict__ W_in,
            const float* __restrict__ b_in,
            const float* __restrict__ W1,
            const float* __restrict__ b1,
            const float* __restrict__ W2,
            const float* __restrict__ b2,
            const float* __restrict__ W_out,
            const float* __restrict__ b_out,
            const int* __restrict__ row,
            const int* __restrict__ col,
            const int* __restrict__ occ,
            float* __restrict__ out,
            float* __restrict__ ws)
{
    __shared__ float xm[TILE][PITCH];
    __shared__ float xv[TILE][PITCH];
    __shared__ float wt[KC][PITCH];
    __shared__ int   scol[TILE];
    __shared__ float prel[TILE][3];
    __shared__ float red[2];

    const int tid   = threadIdx.x;
    const int gbase = blockIdx.x * TILE;

    if (tid < 2) red[tid] = 0.0f;
    if (tid < TILE) {
        int ge = gbase + tid;
        int c  = col[ge];
        int r  = row[ge];
        scol[tid] = c;
        prel[tid][0] = pos_target[r * 3 + 0] - pos_source[c * 3 + 0];
        prel[tid][1] = pos_target[r * 3 + 1] - pos_source[c * 3 + 1];
        prel[tid][2] = pos_target[r * 3 + 2] - pos_source[c * 3 + 2];
    }
    __syncthreads();
    for (int idx = tid; idx < TILE * LDIM; idx += 256) {
        int e = idx >> 7, d = idx & 127;
        int c = scol[e];
        xm[e][d] = latents[c * LDIM + d];
        xv[e][d] = varr[c * LDIM + d];
    }
    if (tid < TILE) {
        float4 t = make_float4(prel[tid][0], prel[tid][1], prel[tid][2], 0.0f);
        *reinterpret_cast<float4*>(&xm[tid][128]) = t;
        *reinterpret_cast<float4*>(&xv[tid][128]) = t;
    }
    // no sync needed here: do_layer starts with __syncthreads()

    do_layer(xm, xv, wt, W_in, b_in, nullptr,   131, gbase);
    do_layer(xm, xv, wt, W1,   b1,   nullptr,   128, gbase);
    do_layer(xm, xv, wt, W2,   b2,   drop_mask, 128, gbase);

    __syncthreads();
    {
        const int e = tid >> 3;
        const int part = tid & 7;
        const int dbase = part * 16;
        float pm = 0.0f, pv = 0.0f;
#pragma unroll
        for (int d = 0; d < 16; d += 4) {
            float4 w4 = *reinterpret_cast<const float4*>(&W_out[dbase + d]);
            float4 m4 = *reinterpret_cast<const float4*>(&xm[e][dbase + d]);
            float4 v4 = *reinterpret_cast<const float4*>(&xv[e][dbase + d]);
            pm += w4.x * m4.x + w4.y * m4.y + w4.z * m4.z + w4.w * m4.w;
            pv += w4.x * w4.x * v4.x + w4.y * w4.y * v4.y + w4.z * w4.z * v4.z + w4.w * w4.w * v4.w;
        }
#pragma unroll
        for (int off = 1; off < 8; off <<= 1) {
            pm += __shfl_xor(pm, off, 64);
            pv += __shfl_xor(pv, off, 64);
        }
        if (part == 0) {
            const int ge = gbase + e;
            float p = pm + b_out[0];
            out[ge] = p;
            float occf = (float)occ[row[ge]];
            out[E_TOT + 2 + ge] = occf;
            float loss = fmaxf(p, 0.0f) - p * occf + log1pf(expf(-fabsf(p)));
            atomicAdd(&red[0], fabsf(pv));
            atomicAdd(&red[1], loss);
        }
    }
    __syncthreads();
    if (tid == 0) {
        atomicAdd(&ws[0], red[0]);
        atomicAdd(&ws[1], red[1]);
    }
}

__global__ void interp_finalize(const float* __restrict__ ws, float* __restrict__ out)
{
    if (threadIdx.x == 0) {
        const float inv = 1.0f / (float)E_TOT;
        out[E_TOT]     = ws[0] * inv;
        out[E_TOT + 1] = ws[1] * inv;
    }
}

extern "C" void kernel_launch(void* const* d_in, const int* in_sizes, int n_in,
                              void* d_out, int out_size, void* d_ws, size_t ws_size,
                              hipStream_t stream) {
    (void)in_sizes; (void)n_in; (void)out_size; (void)ws_size;
    const float* pos_source = (const float*)d_in[0];
    const float* pos_target = (const float*)d_in[1];
    const float* latents    = (const float*)d_in[2];
    const float* varr       = (const float*)d_in[3];
    const float* drop_mask  = (const float*)d_in[4];
    const float* W_in       = (const float*)d_in[5];
    const float* b_in       = (const float*)d_in[6];
    const float* W1         = (const float*)d_in[7];
    const float* b1         = (const float*)d_in[8];
    const float* W2         = (const float*)d_in[9];
    const float* b2         = (const float*)d_in[10];
    const float* W_out      = (const float*)d_in[11];
    const float* b_out      = (const float*)d_in[12];
    const int*   row        = (const int*)d_in[13];
    const int*   col        = (const int*)d_in[14];
    const int*   occ        = (const int*)d_in[15];
    float* out = (float*)d_out;
    float* ws  = (float*)d_ws;

    hipMemsetAsync(d_ws, 0, 2 * sizeof(float), stream);
    interp_main<<<E_TOT / TILE, 256, 0, stream>>>(
        pos_source, pos_target, latents, varr, drop_mask,
        W_in, b_in, W1, b1, W2, b2, W_out, b_out,
        row, col, occ, out, ws);
    interp_finalize<<<1, 64, 0, stream>>>(ws, out);
}

// Round 2
// 499.907 us; speedup vs baseline: 2.6927x; 2.6927x over previous
//
#include <hip/hip_runtime.h>
#include <math.h>

#define E_TOT 262144
#define LDIM  128
#define XP    168            // X row pitch in halves (336 B, 336/16 = 21 odd -> slot-even)
#define XPB   336
#define MIN_VARF 0.001f
#define INV_SQRT2F   0.70710678118654752f
#define INV_SQRT2PIF 0.3989422804014327f

typedef _Float16 half8 __attribute__((ext_vector_type(8)));
typedef float    f32x4 __attribute__((ext_vector_type(4)));

// ---- d_ws byte layout ----
#define RED_OFF   0        // 2 f32 reduction slots
#define BIAS_OFF  256      // 3 layers x 128 f32 (reordered [g*32+t*4+r])
#define WOUT_OFF  1792     // 2 x 128 f32 (W_out row0, W_out row0 squared; reordered)
#define BOUT_OFF  2816     // 1 f32
#define PACK_OFF  4096
#define L0_BYTES  40960    // 5 ksteps * 8 tiles * 64 lanes * 16 B
#define L12_BYTES 32768    // 4 ksteps * ...
#define PK_L0M (PACK_OFF)
#define PK_L0V (PK_L0M + L0_BYTES)
#define PK_L1M (PK_L0V + L0_BYTES)
#define PK_L1V (PK_L1M + L12_BYTES)
#define PK_L2M (PK_L1V + L12_BYTES)
#define PK_L2V (PK_L2M + L12_BYTES)
// end = 217088 bytes

__device__ __forceinline__ short h2s(float x) {
    union U { _Float16 h; short s; } u; u.h = (_Float16)x; return u.s;
}

__device__ __forceinline__ void adf_relu(float& m, float& v) {
    float vv  = fmaxf(v, 1e-6f);
    float sd  = sqrtf(vv);
    float r   = m / sd;
    float cdf = 0.5f * (1.0f + erff(r * INV_SQRT2F));
    float pdf = expf(-0.5f * r * r) * INV_SQRT2PIF;
    float mo  = m * cdf + sd * pdf;
    float vo  = (m * m + vv) * cdf + m * sd * pdf - mo * mo;
    m = mo; v = vo;
}

// Pack weights into fragment-linear f16 layout:
// entry (ks*8 + t)*64 + lane holds A[row = 16t + (lane&15)][k = 32ks + 8*(lane>>4) + j]
__global__ void prep(const float* __restrict__ W_in, const float* __restrict__ b_in,
                     const float* __restrict__ W1,   const float* __restrict__ b1,
                     const float* __restrict__ W2,   const float* __restrict__ b2,
                     const float* __restrict__ W_out,const float* __restrict__ b_out,
                     char* __restrict__ ws)
{
    int idx = blockIdx.x * 256 + threadIdx.x;
    if (idx < 13312) {
        const float* W; int Kfull; long dstoff; bool sq; int entry;
        if (idx < 5120)      { int s = idx / 2560; entry = idx - s * 2560; W = W_in; Kfull = 131; dstoff = s ? PK_L0V : PK_L0M; sq = s; }
        else if (idx < 9216) { int j = idx - 5120; int s = j / 2048; entry = j - s * 2048; W = W1; Kfull = 128; dstoff = s ? PK_L1V : PK_L1M; sq = s; }
        else                 { int j = idx - 9216; int s = j / 2048; entry = j - s * 2048; W = W2; Kfull = 128; dstoff = s ? PK_L2V : PK_L2M; sq = s; }
        int ks   = entry >> 9;
        int rest = entry & 511;
        int t    = rest >> 6;
        int lane = rest & 63;
        int rowi = t * 16 + (lane & 15);
        int k0   = ks * 32 + (lane >> 4) * 8;
        half8 hv;
#pragma unroll
        for (int j = 0; j < 8; ++j) {
            int k = k0 + j;
            float v = (k < Kfull) ? W[rowi * Kfull + k] : 0.0f;
            if (sq) v = v * v;
            hv[j] = (_Float16)v;
        }
        *(half8*)(ws + dstoff + (long)entry * 16) = hv;
    } else if (idx < 13312 + 384) {
        int j = idx - 13312; int layer = j >> 7; int pidx = j & 127;
        int gg = pidx >> 5, t = (pidx >> 2) & 7, r = pidx & 3;
        int n = t * 16 + gg * 4 + r;
        const float* b = layer == 0 ? b_in : (layer == 1 ? b1 : b2);
        ((float*)(ws + BIAS_OFF))[layer * 128 + pidx] = b[n];
    } else if (idx < 13312 + 384 + 256) {
        int j = idx - 13312 - 384; int path = j >> 7; int pidx = j & 127;
        int gg = pidx >> 5, t = (pidx >> 2) & 7, r = pidx & 3;
        int n = t * 16 + gg * 4 + r;
        float v = W_out[n];              // row 0 of [2][128]
        if (path) v = v * v;
        ((float*)(ws + WOUT_OFF))[path * 128 + pidx] = v;
    } else if (idx == 13312 + 384 + 256) {
        ((float*)(ws + BOUT_OFF))[0] = b_out[0];
        ((float*)(ws + RED_OFF))[0] = 0.0f;
        ((float*)(ws + RED_OFF))[1] = 0.0f;
    }
}

__global__ void __launch_bounds__(256)
interp_main(const float* __restrict__ pos_source, const float* __restrict__ pos_target,
            const float* __restrict__ latents,    const float* __restrict__ varr,
            const float* __restrict__ drop_mask,
            const int* __restrict__ row, const int* __restrict__ col, const int* __restrict__ occ,
            float* __restrict__ out, char* __restrict__ ws)
{
    __shared__ __align__(16) short Xm[64][XP];
    __shared__ __align__(16) short Xv[64][XP];

    const int tid  = threadIdx.x;
    const int lane = tid & 63;
    const int w    = tid >> 6;
    const int q    = lane & 15;
    const int g    = lane >> 4;
    const int eb   = w * 16;
    const int gbase = blockIdx.x * 64;
    char* xmb = (char*)&Xm[0][0];
    char* xvb = (char*)&Xv[0][0];

    // ---- stage X (f16) : wave-local, no barriers needed ----
    {
        const int el   = eb + (lane >> 2);
        const int dseg = (lane & 3) * 32;
        const int gei  = gbase + el;
        const int c    = col[gei];
        const f32x4* lm = (const f32x4*)(latents + (long)c * LDIM + dseg);
        const f32x4* lv = (const f32x4*)(varr    + (long)c * LDIM + dseg);
#pragma unroll
        for (int i = 0; i < 8; ++i) {
            f32x4 fm = lm[i], fv = lv[i];
            short4 sm, sv;
            sm.x = h2s(fm[0]); sm.y = h2s(fm[1]); sm.z = h2s(fm[2]); sm.w = h2s(fm[3]);
            sv.x = h2s(fv[0]); sv.y = h2s(fv[1]); sv.z = h2s(fv[2]); sv.w = h2s(fv[3]);
            *(short4*)(xmb + el * XPB + (dseg + i * 4) * 2) = sm;
            *(short4*)(xvb + el * XPB + (dseg + i * 4) * 2) = sv;
        }
        if (lane < 16) {
            const int el2 = eb + lane;
            const int ge2 = gbase + el2;
            const int c2 = col[ge2], r2 = row[ge2];
            short4 p0;
            p0.x = h2s(pos_target[r2 * 3 + 0] - pos_source[c2 * 3 + 0]);
            p0.y = h2s(pos_target[r2 * 3 + 1] - pos_source[c2 * 3 + 1]);
            p0.z = h2s(pos_target[r2 * 3 + 2] - pos_source[c2 * 3 + 2]);
            p0.w = 0;
            *(short4*)(xmb + el2 * XPB + 256) = p0;
            *(short4*)(xvb + el2 * XPB + 256) = p0;
            short4 z; z.x = z.y = z.z = z.w = 0;
#pragma unroll
            for (int j = 1; j < 10; ++j) {
                *(short4*)(xmb + el2 * XPB + 256 + j * 8) = z;
                *(short4*)(xvb + el2 * XPB + 256 + j * 8) = z;
            }
        }
    }

    const int erow = eb + q;
    const int ge   = gbase + erow;
    f32x4 accm[8], accv[8];
    const f32x4 zz = {0.0f, 0.0f, 0.0f, 0.0f};

    for (int layer = 0; layer < 3; ++layer) {
        const int KS = (layer == 0) ? 5 : 4;
        const char* pm; const char* pv;
        if (layer == 0)      { pm = ws + PK_L0M; pv = ws + PK_L0V; }
        else if (layer == 1) { pm = ws + PK_L1M; pv = ws + PK_L1V; }
        else                 { pm = ws + PK_L2M; pv = ws + PK_L2V; }
#pragma unroll
        for (int t = 0; t < 8; ++t) { accm[t] = zz; accv[t] = zz; }

        for (int ks = 0; ks < KS; ++ks) {
            half8 bm = *(const half8*)(xmb + erow * XPB + ks * 64 + g * 16);
            half8 bv = *(const half8*)(xvb + erow * XPB + ks * 64 + g * 16);
            const char* pmk = pm + ks * 8192 + lane * 16;
            const char* pvk = pv + ks * 8192 + lane * 16;
#pragma unroll
            for (int t = 0; t < 8; ++t) {
                half8 am = *(const half8*)(pmk + t * 1024);
                half8 av = *(const half8*)(pvk + t * 1024);
                accm[t] = __builtin_amdgcn_mfma_f32_16x16x32_f16(am, bm, accm[t], 0, 0, 0);
                accv[t] = __builtin_amdgcn_mfma_f32_16x16x32_f16(av, bv, accv[t], 0, 0, 0);
            }
        }

        const f32x4* bp = (const f32x4*)(ws + BIAS_OFF) + layer * 32 + g * 8;
        if (layer < 2) {
#pragma unroll
            for (int t = 0; t < 8; ++t) {
                f32x4 b4 = bp[t];
                float m0 = accm[t][0] + b4[0], m1 = accm[t][1] + b4[1];
                float m2 = accm[t][2] + b4[2], m3 = accm[t][3] + b4[3];
                float v0 = accv[t][0], v1 = accv[t][1], v2 = accv[t][2], v3 = accv[t][3];
                adf_relu(m0, v0); adf_relu(m1, v1); adf_relu(m2, v2); adf_relu(m3, v3);
                short4 sm; sm.x = h2s(m0); sm.y = h2s(m1); sm.z = h2s(m2); sm.w = h2s(m3);
                short4 sv; sv.x = h2s(v0); sv.y = h2s(v1); sv.z = h2s(v2); sv.w = h2s(v3);
                *(short4*)(xmb + erow * XPB + t * 32 + g * 8) = sm;
                *(short4*)(xvb + erow * XPB + t * 32 + g * 8) = sv;
            }
        } else {
            float pmacc = 0.0f, pvacc = 0.0f;
            const f32x4* wmp = (const f32x4*)(ws + WOUT_OFF);
            const f32x4* dmp = (const f32x4*)drop_mask + (size_t)ge * 32 + g;
#pragma unroll
            for (int t = 0; t < 8; ++t) {
                f32x4 b4 = bp[t];
                f32x4 d4 = dmp[t * 4];
                f32x4 w4 = wmp[g * 8 + t];
                f32x4 s4 = wmp[32 + g * 8 + t];
                float m0 = (accm[t][0] + b4[0]) * d4[0];
                float m1 = (accm[t][1] + b4[1]) * d4[1];
                float m2 = (accm[t][2] + b4[2]) * d4[2];
                float m3 = (accm[t][3] + b4[3]) * d4[3];
                float v0 = accv[t][0] * d4[0] * d4[0] + MIN_VARF;
                float v1 = accv[t][1] * d4[1] * d4[1] + MIN_VARF;
                float v2 = accv[t][2] * d4[2] * d4[2] + MIN_VARF;
                float v3 = accv[t][3] * d4[3] * d4[3] + MIN_VARF;
                pmacc += w4[0] * m0 + w4[1] * m1 + w4[2] * m2 + w4[3] * m3;
                pvacc += s4[0] * v0 + s4[1] * v1 + s4[2] * v2 + s4[3] * v3;
            }
            pmacc += __shfl_xor(pmacc, 16, 64);
            pmacc += __shfl_xor(pmacc, 32, 64);
            pvacc += __shfl_xor(pvacc, 16, 64);
            pvacc += __shfl_xor(pvacc, 32, 64);
            float bout = *(const float*)(ws + BOUT_OFF);
            float p = pmacc + bout;
            float occf = (float)occ[row[ge]];
            if (lane < 16) {
                out[ge] = p;
                out[E_TOT + 2 + ge] = occf;
            }
            float loss = fmaxf(p, 0.0f) - p * occf + log1pf(expf(-fabsf(p)));
            float al = fabsf(pvacc);
#pragma unroll
            for (int off = 1; off < 16; off <<= 1) {
                al   += __shfl_xor(al, off, 64);
                loss += __shfl_xor(loss, off, 64);
            }
            if (lane == 0) {
                atomicAdd((float*)(ws + RED_OFF), al);
                atomicAdd((float*)(ws + RED_OFF) + 1, loss);
            }
        }
    }
}

__global__ void interp_finalize(const char* __restrict__ ws, float* __restrict__ out)
{
    if (threadIdx.x == 0) {
        const float inv = 1.0f / (float)E_TOT;
        out[E_TOT]     = ((const float*)(ws + RED_OFF))[0] * inv;
        out[E_TOT + 1] = ((const float*)(ws + RED_OFF))[1] * inv;
    }
}

extern "C" void kernel_launch(void* const* d_in, const int* in_sizes, int n_in,
                              void* d_out, int out_size, void* d_ws, size_t ws_size,
                              hipStream_t stream) {
    (void)in_sizes; (void)n_in; (void)out_size; (void)ws_size;
    const float* pos_source = (const float*)d_in[0];
    const float* pos_target = (const float*)d_in[1];
    const float* latents    = (const float*)d_in[2];
    const float* varr       = (const float*)d_in[3];
    const float* drop_mask  = (const float*)d_in[4];
    const float* W_in       = (const float*)d_in[5];
    const float* b_in       = (const float*)d_in[6];
    const float* W1         = (const float*)d_in[7];
    const float* b1         = (const float*)d_in[8];
    const float* W2         = (const float*)d_in[9];
    const float* b2         = (const float*)d_in[10];
    const float* W_out      = (const float*)d_in[11];
    const float* b_out      = (const float*)d_in[12];
    const int*   row        = (const int*)d_in[13];
    const int*   col        = (const int*)d_in[14];
    const int*   occ        = (const int*)d_in[15];
    float* out = (float*)d_out;
    char*  ws  = (char*)d_ws;

    prep<<<55, 256, 0, stream>>>(W_in, b_in, W1, b1, W2, b2, W_out, b_out, ws);
    interp_main<<<E_TOT / 64, 256, 0, stream>>>(
        pos_source, pos_target, latents, varr, drop_mask,
        row, col, occ, out, ws);
    interp_finalize<<<1, 64, 0, stream>>>(ws, out);
}

// Round 3
// 469.602 us; speedup vs baseline: 2.8665x; 1.0645x over previous
//
#include <hip/hip_runtime.h>
#include <math.h>

#define E_TOT 262144
#define LDIM  128
#define XPB   272            // X row pitch in bytes (17*16 -> slot-odd, conflict-free-ish)
#define MIN_VARF 0.001f
#define INV_SQRT2PIF 0.3989422804014327f

typedef _Float16 half8 __attribute__((ext_vector_type(8)));
typedef float    f32x4 __attribute__((ext_vector_type(4)));

// ---- d_ws byte layout ----
#define RED_OFF   0        // 2 f32 reduction slots
#define BIAS_OFF  256      // 3 layers x 128 f32 (reordered [g*32+t*4+r])
#define WOUT_OFF  1792     // 2 x 128 f32 (W_out row0, W_out row0^2; reordered)
#define BOUT_OFF  2816     // 1 f32
#define PK_L0     4096     // 5 ksteps * 8 tiles * 64 lanes * 16 B = 40960
#define PK_L1     45056    // 4 ksteps * 8192 = 32768
#define PK_L2     77824    // 32768 -> end 110592

__device__ __forceinline__ short h2s(float x) {
    union U { _Float16 h; short s; } u; u.h = (_Float16)x; return u.s;
}

// lean ADF-ReLU: rsq-based sqrt/div, native exp, Winitzki erf (abs err ~1.3e-4)
__device__ __forceinline__ void adf_relu(float& m, float& v) {
    float vv = fmaxf(v, 1e-6f);
    float is = __builtin_amdgcn_rsqf(vv);    // 1/sd
    float sd = vv * is;                      // sqrt(vv)
    float r  = m * is;
    float qq = 0.5f * r * r;                 // u^2, u = r/sqrt(2)
    float sp = sd * __expf(-qq) * INV_SQRT2PIF;   // sd * pdf
    const float A = 0.147f;
    float aq  = A * qq;
    float num = qq * (1.27323954f + aq);     // u^2*(4/pi + a u^2)
    float den = 1.0f + aq;
    float z   = -num * __builtin_amdgcn_rcpf(den);
    float wv  = 1.0f - __expf(z);
    float s   = wv * __builtin_amdgcn_rsqf(fmaxf(wv, 1e-20f));  // sqrt(wv)
    float serf = copysignf(s, m);
    float cdf  = 0.5f + 0.5f * serf;
    float mo = fmaf(m, cdf, sp);
    float vo = fmaf(fmaf(m, m, vv), cdf, fmaf(m, sp, -mo * mo));
    m = mo; v = vo;
}

// Pack W (mean path only) into fragment-linear f16:
// entry (ks*8 + t)*64 + lane holds A[row = 16t + (lane&15)][k = 32ks + 8*(lane>>4) + j]
__global__ void prep(const float* __restrict__ W_in, const float* __restrict__ b_in,
                     const float* __restrict__ W1,   const float* __restrict__ b1,
                     const float* __restrict__ W2,   const float* __restrict__ b2,
                     const float* __restrict__ W_out,const float* __restrict__ b_out,
                     char* __restrict__ ws)
{
    int idx = blockIdx.x * 256 + threadIdx.x;
    if (idx < 6656) {
        const float* W; int Kfull; long dstoff; int entry;
        if (idx < 2560)      { entry = idx;        W = W_in; Kfull = 131; dstoff = PK_L0; }
        else if (idx < 4608) { entry = idx - 2560; W = W1;   Kfull = 128; dstoff = PK_L1; }
        else                 { entry = idx - 4608; W = W2;   Kfull = 128; dstoff = PK_L2; }
        int ks   = entry >> 9;
        int rest = entry & 511;
        int t    = rest >> 6;
        int lane = rest & 63;
        int rowi = t * 16 + (lane & 15);
        int k0   = ks * 32 + (lane >> 4) * 8;
        half8 hv;
#pragma unroll
        for (int j = 0; j < 8; ++j) {
            int k = k0 + j;
            hv[j] = (_Float16)((k < Kfull) ? W[rowi * Kfull + k] : 0.0f);
        }
        *(half8*)(ws + dstoff + (long)entry * 16) = hv;
    } else if (idx < 6656 + 384) {
        int j = idx - 6656; int layer = j >> 7; int pidx = j & 127;
        int gg = pidx >> 5, t = (pidx >> 2) & 7, r = pidx & 3;
        int n = t * 16 + gg * 4 + r;
        const float* b = layer == 0 ? b_in : (layer == 1 ? b1 : b2);
        ((float*)(ws + BIAS_OFF))[layer * 128 + pidx] = b[n];
    } else if (idx < 6656 + 384 + 256) {
        int j = idx - 6656 - 384; int path = j >> 7; int pidx = j & 127;
        int gg = pidx >> 5, t = (pidx >> 2) & 7, r = pidx & 3;
        int n = t * 16 + gg * 4 + r;
        float v = W_out[n];
        if (path) v = v * v;
        ((float*)(ws + WOUT_OFF))[path * 128 + pidx] = v;
    } else if (idx == 6656 + 384 + 256) {
        ((float*)(ws + BOUT_OFF))[0] = b_out[0];
        ((float*)(ws + RED_OFF))[0] = 0.0f;
        ((float*)(ws + RED_OFF))[1] = 0.0f;
    }
}

__global__ void __launch_bounds__(256, 4)
interp_main(const float* __restrict__ pos_source, const float* __restrict__ pos_target,
            const float* __restrict__ latents,    const float* __restrict__ varr,
            const float* __restrict__ drop_mask,
            const int* __restrict__ row, const int* __restrict__ col, const int* __restrict__ occ,
            float* __restrict__ out, char* __restrict__ ws)
{
    __shared__ __align__(16) short Xm[64][XPB / 2];
    __shared__ __align__(16) short Xv[64][XPB / 2];

    const int tid  = threadIdx.x;
    const int lane = tid & 63;
    const int w    = tid >> 6;
    const int q    = lane & 15;
    const int g    = lane >> 4;
    const int eb   = w * 16;
    const int gbase = blockIdx.x * 64;
    const int erow = eb + q;
    const int ge   = gbase + erow;
    char* xmb = (char*)&Xm[0][0];
    char* xvb = (char*)&Xv[0][0];

    const int c0 = col[ge];
    const int r0 = row[ge];
    const float px = pos_target[r0 * 3 + 0] - pos_source[c0 * 3 + 0];
    const float py = pos_target[r0 * 3 + 1] - pos_source[c0 * 3 + 1];
    const float pz = pos_target[r0 * 3 + 2] - pos_source[c0 * 3 + 2];

    f32x4 accm[8], accv[8];
    const f32x4 zz = {0.0f, 0.0f, 0.0f, 0.0f};

    // ================= layer 0: B from global, A from packed ws =================
#pragma unroll
    for (int t = 0; t < 8; ++t) { accm[t] = zz; accv[t] = zz; }
    {
        const float* lm = latents + (long)c0 * LDIM;
        const float* lv = varr    + (long)c0 * LDIM;
        const char*  pk = ws + PK_L0;
#pragma unroll
        for (int ks = 0; ks < 4; ++ks) {
            const f32x4* am4 = (const f32x4*)(lm + ks * 32 + g * 8);
            const f32x4* av4 = (const f32x4*)(lv + ks * 32 + g * 8);
            f32x4 fm0 = am4[0], fm1 = am4[1];
            f32x4 fv0 = av4[0], fv1 = av4[1];
            half8 bm, bv;
#pragma unroll
            for (int j = 0; j < 4; ++j) {
                bm[j] = (_Float16)fm0[j]; bm[j + 4] = (_Float16)fm1[j];
                bv[j] = (_Float16)fv0[j]; bv[j + 4] = (_Float16)fv1[j];
            }
            const char* pmk = pk + ks * 8192 + lane * 16;
#pragma unroll
            for (int t = 0; t < 8; ++t) {
                half8 am = *(const half8*)(pmk + t * 1024);
                half8 av = am * am;
                accm[t] = __builtin_amdgcn_mfma_f32_16x16x32_f16(am, bm, accm[t], 0, 0, 0);
                accv[t] = __builtin_amdgcn_mfma_f32_16x16x32_f16(av, bv, accv[t], 0, 0, 0);
            }
        }
        // ks = 4: pos_rel (k = 128..130), register-sourced B
        half8 bpos = {(_Float16)0.f, (_Float16)0.f, (_Float16)0.f, (_Float16)0.f,
                      (_Float16)0.f, (_Float16)0.f, (_Float16)0.f, (_Float16)0.f};
        if (g == 0) { bpos[0] = (_Float16)px; bpos[1] = (_Float16)py; bpos[2] = (_Float16)pz; }
        const char* pmk = pk + 4 * 8192 + lane * 16;
#pragma unroll
        for (int t = 0; t < 8; ++t) {
            half8 am = *(const half8*)(pmk + t * 1024);
            half8 av = am * am;
            accm[t] = __builtin_amdgcn_mfma_f32_16x16x32_f16(am, bpos, accm[t], 0, 0, 0);
            accv[t] = __builtin_amdgcn_mfma_f32_16x16x32_f16(av, bpos, accv[t], 0, 0, 0);
        }
        // epilogue: bias + adf_relu -> LDS
        const f32x4* bp = (const f32x4*)(ws + BIAS_OFF) + g * 8;
#pragma unroll
        for (int t = 0; t < 8; ++t) {
            f32x4 b4 = bp[t];
            float m0 = accm[t][0] + b4[0], m1 = accm[t][1] + b4[1];
            float m2 = accm[t][2] + b4[2], m3 = accm[t][3] + b4[3];
            float v0 = accv[t][0], v1 = accv[t][1], v2 = accv[t][2], v3 = accv[t][3];
            adf_relu(m0, v0); adf_relu(m1, v1); adf_relu(m2, v2); adf_relu(m3, v3);
            short4 sm; sm.x = h2s(m0); sm.y = h2s(m1); sm.z = h2s(m2); sm.w = h2s(m3);
            short4 sv; sv.x = h2s(v0); sv.y = h2s(v1); sv.z = h2s(v2); sv.w = h2s(v3);
            *(short4*)(xmb + erow * XPB + t * 32 + g * 8) = sm;
            *(short4*)(xvb + erow * XPB + t * 32 + g * 8) = sv;
        }
    }

    // ================= layers 1,2: B from LDS =================
    for (int layer = 1; layer < 3; ++layer) {
        const char* pk = ws + (layer == 1 ? PK_L1 : PK_L2);
#pragma unroll
        for (int t = 0; t < 8; ++t) { accm[t] = zz; accv[t] = zz; }
#pragma unroll
        for (int ks = 0; ks < 4; ++ks) {
            half8 bm = *(const half8*)(xmb + erow * XPB + ks * 64 + g * 16);
            half8 bv = *(const half8*)(xvb + erow * XPB + ks * 64 + g * 16);
            const char* pmk = pk + ks * 8192 + lane * 16;
#pragma unroll
            for (int t = 0; t < 8; ++t) {
                half8 am = *(const half8*)(pmk + t * 1024);
                half8 av = am * am;
                accm[t] = __builtin_amdgcn_mfma_f32_16x16x32_f16(am, bm, accm[t], 0, 0, 0);
                accv[t] = __builtin_amdgcn_mfma_f32_16x16x32_f16(av, bv, accv[t], 0, 0, 0);
            }
        }
        const f32x4* bp = (const f32x4*)(ws + BIAS_OFF) + layer * 32 + g * 8;
        if (layer == 1) {
#pragma unroll
            for (int t = 0; t < 8; ++t) {
                f32x4 b4 = bp[t];
                float m0 = accm[t][0] + b4[0], m1 = accm[t][1] + b4[1];
                float m2 = accm[t][2] + b4[2], m3 = accm[t][3] + b4[3];
                float v0 = accv[t][0], v1 = accv[t][1], v2 = accv[t][2], v3 = accv[t][3];
                adf_relu(m0, v0); adf_relu(m1, v1); adf_relu(m2, v2); adf_relu(m3, v3);
                short4 sm; sm.x = h2s(m0); sm.y = h2s(m1); sm.z = h2s(m2); sm.w = h2s(m3);
                short4 sv; sv.x = h2s(v0); sv.y = h2s(v1); sv.z = h2s(v2); sv.w = h2s(v3);
                *(short4*)(xmb + erow * XPB + t * 32 + g * 8) = sm;
                *(short4*)(xvb + erow * XPB + t * 32 + g * 8) = sv;
            }
        } else {
            float pmacc = 0.0f, pvacc = 0.0f;
            const f32x4* wmp = (const f32x4*)(ws + WOUT_OFF);
            const f32x4* dmp = (const f32x4*)drop_mask + (size_t)ge * 32 + g;
#pragma unroll
            for (int t = 0; t < 8; ++t) {
                f32x4 b4 = bp[t];
                f32x4 d4 = dmp[t * 4];
                f32x4 w4 = wmp[g * 8 + t];
                f32x4 s4 = wmp[32 + g * 8 + t];
                float m0 = (accm[t][0] + b4[0]) * d4[0];
                float m1 = (accm[t][1] + b4[1]) * d4[1];
                float m2 = (accm[t][2] + b4[2]) * d4[2];
                float m3 = (accm[t][3] + b4[3]) * d4[3];
                float v0 = accv[t][0] * d4[0] * d4[0] + MIN_VARF;
                float v1 = accv[t][1] * d4[1] * d4[1] + MIN_VARF;
                float v2 = accv[t][2] * d4[2] * d4[2] + MIN_VARF;
                float v3 = accv[t][3] * d4[3] * d4[3] + MIN_VARF;
                pmacc += w4[0] * m0 + w4[1] * m1 + w4[2] * m2 + w4[3] * m3;
                pvacc += s4[0] * v0 + s4[1] * v1 + s4[2] * v2 + s4[3] * v3;
            }
            pmacc += __shfl_xor(pmacc, 16, 64);
            pmacc += __shfl_xor(pmacc, 32, 64);
            pvacc += __shfl_xor(pvacc, 16, 64);
            pvacc += __shfl_xor(pvacc, 32, 64);
            float bout = *(const float*)(ws + BOUT_OFF);
            float p = pmacc + bout;
            float occf = (float)occ[r0];
            if (lane < 16) {
                out[ge] = p;
                out[E_TOT + 2 + ge] = occf;
            }
            float a = fabsf(p);
            float loss = fmaxf(p, 0.0f) - p * occf + __logf(1.0f + __expf(-a));
            float al = fabsf(pvacc);
#pragma unroll
            for (int off = 1; off < 16; off <<= 1) {
                al   += __shfl_xor(al, off, 64);
                loss += __shfl_xor(loss, off, 64);
            }
            if (lane == 0) {
                atomicAdd((float*)(ws + RED_OFF), al);
                atomicAdd((float*)(ws + RED_OFF) + 1, loss);
            }
        }
    }
}

__global__ void interp_finalize(const char* __restrict__ ws, float* __restrict__ out)
{
    if (threadIdx.x == 0) {
        const float inv = 1.0f / (float)E_TOT;
        out[E_TOT]     = ((const float*)(ws + RED_OFF))[0] * inv;
        out[E_TOT + 1] = ((const float*)(ws + RED_OFF))[1] * inv;
    }
}

extern "C" void kernel_launch(void* const* d_in, const int* in_sizes, int n_in,
                              void* d_out, int out_size, void* d_ws, size_t ws_size,
                              hipStream_t stream) {
    (void)in_sizes; (void)n_in; (void)out_size; (void)ws_size;
    const float* pos_source = (const float*)d_in[0];
    const float* pos_target = (const float*)d_in[1];
    const float* latents    = (const float*)d_in[2];
    const float* varr       = (const float*)d_in[3];
    const float* drop_mask  = (const float*)d_in[4];
    const float* W_in       = (const float*)d_in[5];
    const float* b_in       = (const float*)d_in[6];
    const float* W1         = (const float*)d_in[7];
    const float* b1         = (const float*)d_in[8];
    const float* W2         = (const float*)d_in[9];
    const float* b2         = (const float*)d_in[10];
    const float* W_out      = (const float*)d_in[11];
    const float* b_out      = (const float*)d_in[12];
    const int*   row        = (const int*)d_in[13];
    const int*   col        = (const int*)d_in[14];
    const int*   occ        = (const int*)d_in[15];
    float* out = (float*)d_out;
    char*  ws  = (char*)d_ws;

    prep<<<29, 256, 0, stream>>>(W_in, b_in, W1, b1, W2, b2, W_out, b_out, ws);
    interp_main<<<E_TOT / 64, 256, 0, stream>>>(
        pos_source, pos_target, latents, varr, drop_mask,
        row, col, occ, out, ws);
    interp_finalize<<<1, 64, 0, stream>>>(ws, out);
}

// Round 4
// 463.674 us; speedup vs baseline: 2.9031x; 1.0128x over previous
//
#include <hip/hip_runtime.h>
#include <math.h>

#define E_TOT 262144
#define LDIM  128
#define XPB   272            // X row pitch in bytes
#define MIN_VARF 0.001f
#define INV_SQRT2PIF 0.3989422804014327f

typedef _Float16 half8 __attribute__((ext_vector_type(8)));
typedef float    f32x4 __attribute__((ext_vector_type(4)));
typedef __attribute__((address_space(1))) const unsigned int g32;
typedef __attribute__((address_space(3))) unsigned int l32;

// ---- d_ws byte layout ----
#define RED_OFF   0        // 2 f32 reduction slots
#define BIAS_OFF  256      // 3 layers x 128 f32 (reordered [g*32+t*4+r])
#define WOUT_OFF  1792     // 2 x 128 f32 (W_out row0, W_out row0^2; reordered)
#define BOUT_OFF  2816     // 1 f32
#define PK_L0     4096     // 5 ksteps * 8 tiles * 64 lanes * 16 B = 40960
#define PK_L1     45056    // 4 ksteps * 8192 = 32768
#define PK_L2     77824    // 32768 -> end 110592

__device__ __forceinline__ short h2s(float x) {
    union U { _Float16 h; short s; } u; u.h = (_Float16)x; return u.s;
}

// lean ADF-ReLU: rsq-based sqrt/div, native exp, Winitzki erf (abs err ~1.3e-4)
__device__ __forceinline__ void adf_relu(float& m, float& v) {
    float vv = fmaxf(v, 1e-6f);
    float is = __builtin_amdgcn_rsqf(vv);    // 1/sd
    float sd = vv * is;                      // sqrt(vv)
    float r  = m * is;
    float qq = 0.5f * r * r;                 // u^2, u = r/sqrt(2)
    float sp = sd * __expf(-qq) * INV_SQRT2PIF;   // sd * pdf
    const float A = 0.147f;
    float aq  = A * qq;
    float num = qq * (1.27323954f + aq);     // u^2*(4/pi + a u^2)
    float den = 1.0f + aq;
    float z   = -num * __builtin_amdgcn_rcpf(den);
    float wv  = 1.0f - __expf(z);
    float s   = wv * __builtin_amdgcn_rsqf(fmaxf(wv, 1e-20f));  // sqrt(wv)
    float serf = copysignf(s, m);
    float cdf  = 0.5f + 0.5f * serf;
    float mo = fmaf(m, cdf, sp);
    float vo = fmaf(fmaf(m, m, vv), cdf, fmaf(m, sp, -mo * mo));
    m = mo; v = vo;
}

// Pack W (mean path only) into fragment-linear f16:
// entry (ks*8 + t)*64 + lane holds A[row = 16t + (lane&15)][k = 32ks + 8*(lane>>4) + j]
__global__ void prep(const float* __restrict__ W_in, const float* __restrict__ b_in,
                     const float* __restrict__ W1,   const float* __restrict__ b1,
                     const float* __restrict__ W2,   const float* __restrict__ b2,
                     const float* __restrict__ W_out,const float* __restrict__ b_out,
                     char* __restrict__ ws)
{
    int idx = blockIdx.x * 256 + threadIdx.x;
    if (idx < 6656) {
        const float* W; int Kfull; long dstoff; int entry;
        if (idx < 2560)      { entry = idx;        W = W_in; Kfull = 131; dstoff = PK_L0; }
        else if (idx < 4608) { entry = idx - 2560; W = W1;   Kfull = 128; dstoff = PK_L1; }
        else                 { entry = idx - 4608; W = W2;   Kfull = 128; dstoff = PK_L2; }
        int ks   = entry >> 9;
        int rest = entry & 511;
        int t    = rest >> 6;
        int lane = rest & 63;
        int rowi = t * 16 + (lane & 15);
        int k0   = ks * 32 + (lane >> 4) * 8;
        half8 hv;
#pragma unroll
        for (int j = 0; j < 8; ++j) {
            int k = k0 + j;
            hv[j] = (_Float16)((k < Kfull) ? W[rowi * Kfull + k] : 0.0f);
        }
        *(half8*)(ws + dstoff + (long)entry * 16) = hv;
    } else if (idx < 6656 + 384) {
        int j = idx - 6656; int layer = j >> 7; int pidx = j & 127;
        int gg = pidx >> 5, t = (pidx >> 2) & 7, r = pidx & 3;
        int n = t * 16 + gg * 4 + r;
        const float* b = layer == 0 ? b_in : (layer == 1 ? b1 : b2);
        ((float*)(ws + BIAS_OFF))[layer * 128 + pidx] = b[n];
    } else if (idx < 6656 + 384 + 256) {
        int j = idx - 6656 - 384; int path = j >> 7; int pidx = j & 127;
        int gg = pidx >> 5, t = (pidx >> 2) & 7, r = pidx & 3;
        int n = t * 16 + gg * 4 + r;
        float v = W_out[n];
        if (path) v = v * v;
        ((float*)(ws + WOUT_OFF))[path * 128 + pidx] = v;
    } else if (idx == 6656 + 384 + 256) {
        ((float*)(ws + BOUT_OFF))[0] = b_out[0];
        ((float*)(ws + RED_OFF))[0] = 0.0f;
        ((float*)(ws + RED_OFF))[1] = 0.0f;
    }
}

__global__ void __launch_bounds__(256, 2)
interp_main(const float* __restrict__ pos_source, const float* __restrict__ pos_target,
            const float* __restrict__ latents,    const float* __restrict__ varr,
            const float* __restrict__ drop_mask,
            const int* __restrict__ row, const int* __restrict__ col, const int* __restrict__ occ,
            float* __restrict__ out, char* __restrict__ ws)
{
    __shared__ __align__(16) char  Wl[40960];
    __shared__ __align__(16) short Xm[64][XPB / 2];
    __shared__ __align__(16) short Xv[64][XPB / 2];
    __shared__ __align__(16) float cbuf[648];

    const int tid  = threadIdx.x;
    const int lane = tid & 63;
    const int w    = tid >> 6;
    const int q    = lane & 15;
    const int g    = lane >> 4;
    const int erow = w * 16 + q;
    const int gbase = blockIdx.x * 64;
    const int ge   = gbase + erow;
    char* xmb = (char*)&Xm[0][0];
    char* xvb = (char*)&Xv[0][0];

    // ---- issue async stage of L0 weights into LDS ----
    {
        const char* src = ws + PK_L0;
        for (int off = w * 1024; off < 40960; off += 4096)
            __builtin_amdgcn_global_load_lds((g32*)(src + off + lane * 16), (l32*)(Wl + off), 16, 0, 0);
    }
    // ---- stage biases / W_out / b_out into LDS (cbuf floats: bias@0, wout@384, bout@640) ----
    for (int i = tid; i < 162; i += 256)
        ((f32x4*)cbuf)[i] = ((const f32x4*)(ws + BIAS_OFF))[i];

    // ---- prefetch: mask (nt) into regs, occ, pos_rel, L0 B-fragments ----
    const int c0 = col[ge];
    const int r0 = row[ge];
    f32x4 md[8];
    {
        const f32x4* dmp = (const f32x4*)drop_mask + (size_t)ge * 32 + g;
#pragma unroll
        for (int t = 0; t < 8; ++t) md[t] = __builtin_nontemporal_load(dmp + t * 4);
    }
    const float occf = (float)occ[r0];
    const float px = pos_target[r0 * 3 + 0] - pos_source[c0 * 3 + 0];
    const float py = pos_target[r0 * 3 + 1] - pos_source[c0 * 3 + 1];
    const float pz = pos_target[r0 * 3 + 2] - pos_source[c0 * 3 + 2];

    half8 bm4[4], bv4[4];
    {
        const float* lm = latents + (long)c0 * LDIM;
        const float* lv = varr    + (long)c0 * LDIM;
#pragma unroll
        for (int ks = 0; ks < 4; ++ks) {
            const f32x4* am4 = (const f32x4*)(lm + ks * 32 + g * 8);
            const f32x4* av4 = (const f32x4*)(lv + ks * 32 + g * 8);
            f32x4 fm0 = am4[0], fm1 = am4[1];
            f32x4 fv0 = av4[0], fv1 = av4[1];
            half8 bm, bv;
#pragma unroll
            for (int j = 0; j < 4; ++j) {
                bm[j] = (_Float16)fm0[j]; bm[j + 4] = (_Float16)fm1[j];
                bv[j] = (_Float16)fv0[j]; bv[j + 4] = (_Float16)fv1[j];
            }
            bm4[ks] = bm; bv4[ks] = bv;
        }
    }

    f32x4 accm[8], accv[8];
    const f32x4 zz = {0.0f, 0.0f, 0.0f, 0.0f};
#pragma unroll
    for (int t = 0; t < 8; ++t) { accm[t] = zz; accv[t] = zz; }

    asm volatile("s_waitcnt vmcnt(0)" ::: "memory");
    __syncthreads();

    // ================= layer 0: B from regs, A from LDS =================
    {
#pragma unroll
        for (int ks = 0; ks < 4; ++ks) {
            const char* pmk = Wl + ks * 8192 + lane * 16;
            half8 bm = bm4[ks], bv = bv4[ks];
#pragma unroll
            for (int t = 0; t < 8; ++t) {
                half8 am = *(const half8*)(pmk + t * 1024);
                half8 av = am * am;
                accm[t] = __builtin_amdgcn_mfma_f32_16x16x32_f16(am, bm, accm[t], 0, 0, 0);
                accv[t] = __builtin_amdgcn_mfma_f32_16x16x32_f16(av, bv, accv[t], 0, 0, 0);
            }
        }
        half8 bpos = {(_Float16)0.f, (_Float16)0.f, (_Float16)0.f, (_Float16)0.f,
                      (_Float16)0.f, (_Float16)0.f, (_Float16)0.f, (_Float16)0.f};
        if (g == 0) { bpos[0] = (_Float16)px; bpos[1] = (_Float16)py; bpos[2] = (_Float16)pz; }
        const char* pmk = Wl + 4 * 8192 + lane * 16;
#pragma unroll
        for (int t = 0; t < 8; ++t) {
            half8 am = *(const half8*)(pmk + t * 1024);
            half8 av = am * am;
            accm[t] = __builtin_amdgcn_mfma_f32_16x16x32_f16(am, bpos, accm[t], 0, 0, 0);
            accv[t] = __builtin_amdgcn_mfma_f32_16x16x32_f16(av, bpos, accv[t], 0, 0, 0);
        }
    }

    // all waves done reading W_L0; kick L1 staging, then do L0 epilogue under it
    __syncthreads();
    {
        const char* src = ws + PK_L1;
        for (int off = w * 1024; off < 32768; off += 4096)
            __builtin_amdgcn_global_load_lds((g32*)(src + off + lane * 16), (l32*)(Wl + off), 16, 0, 0);
    }
    {
        const float* bp = cbuf + g * 32;
#pragma unroll
        for (int t = 0; t < 8; ++t) {
            float m0 = accm[t][0] + bp[t * 4 + 0], m1 = accm[t][1] + bp[t * 4 + 1];
            float m2 = accm[t][2] + bp[t * 4 + 2], m3 = accm[t][3] + bp[t * 4 + 3];
            float v0 = accv[t][0], v1 = accv[t][1], v2 = accv[t][2], v3 = accv[t][3];
            adf_relu(m0, v0); adf_relu(m1, v1); adf_relu(m2, v2); adf_relu(m3, v3);
            short4 sm; sm.x = h2s(m0); sm.y = h2s(m1); sm.z = h2s(m2); sm.w = h2s(m3);
            short4 sv; sv.x = h2s(v0); sv.y = h2s(v1); sv.z = h2s(v2); sv.w = h2s(v3);
            *(short4*)(xmb + erow * XPB + t * 32 + g * 8) = sm;
            *(short4*)(xvb + erow * XPB + t * 32 + g * 8) = sv;
        }
    }
    asm volatile("s_waitcnt vmcnt(0)" ::: "memory");
    __syncthreads();

    // ================= layer 1: B from X LDS, A from W LDS =================
#pragma unroll
    for (int t = 0; t < 8; ++t) { accm[t] = zz; accv[t] = zz; }
#pragma unroll
    for (int ks = 0; ks < 4; ++ks) {
        half8 bm = *(const half8*)(xmb + erow * XPB + ks * 64 + g * 16);
        half8 bv = *(const half8*)(xvb + erow * XPB + ks * 64 + g * 16);
        const char* pmk = Wl + ks * 8192 + lane * 16;
#pragma unroll
        for (int t = 0; t < 8; ++t) {
            half8 am = *(const half8*)(pmk + t * 1024);
            half8 av = am * am;
            accm[t] = __builtin_amdgcn_mfma_f32_16x16x32_f16(am, bm, accm[t], 0, 0, 0);
            accv[t] = __builtin_amdgcn_mfma_f32_16x16x32_f16(av, bv, accv[t], 0, 0, 0);
        }
    }

    __syncthreads();
    {
        const char* src = ws + PK_L2;
        for (int off = w * 1024; off < 32768; off += 4096)
            __builtin_amdgcn_global_load_lds((g32*)(src + off + lane * 16), (l32*)(Wl + off), 16, 0, 0);
    }
    {
        const float* bp = cbuf + 128 + g * 32;
#pragma unroll
        for (int t = 0; t < 8; ++t) {
            float m0 = accm[t][0] + bp[t * 4 + 0], m1 = accm[t][1] + bp[t * 4 + 1];
            float m2 = accm[t][2] + bp[t * 4 + 2], m3 = accm[t][3] + bp[t * 4 + 3];
            float v0 = accv[t][0], v1 = accv[t][1], v2 = accv[t][2], v3 = accv[t][3];
            adf_relu(m0, v0); adf_relu(m1, v1); adf_relu(m2, v2); adf_relu(m3, v3);
            short4 sm; sm.x = h2s(m0); sm.y = h2s(m1); sm.z = h2s(m2); sm.w = h2s(m3);
            short4 sv; sv.x = h2s(v0); sv.y = h2s(v1); sv.z = h2s(v2); sv.w = h2s(v3);
            *(short4*)(xmb + erow * XPB + t * 32 + g * 8) = sm;
            *(short4*)(xvb + erow * XPB + t * 32 + g * 8) = sv;
        }
    }
    asm volatile("s_waitcnt vmcnt(0)" ::: "memory");
    __syncthreads();

    // ================= layer 2 =================
#pragma unroll
    for (int t = 0; t < 8; ++t) { accm[t] = zz; accv[t] = zz; }
#pragma unroll
    for (int ks = 0; ks < 4; ++ks) {
        half8 bm = *(const half8*)(xmb + erow * XPB + ks * 64 + g * 16);
        half8 bv = *(const half8*)(xvb + erow * XPB + ks * 64 + g * 16);
        const char* pmk = Wl + ks * 8192 + lane * 16;
#pragma unroll
        for (int t = 0; t < 8; ++t) {
            half8 am = *(const half8*)(pmk + t * 1024);
            half8 av = am * am;
            accm[t] = __builtin_amdgcn_mfma_f32_16x16x32_f16(am, bm, accm[t], 0, 0, 0);
            accv[t] = __builtin_amdgcn_mfma_f32_16x16x32_f16(av, bv, accv[t], 0, 0, 0);
        }
    }

    // ================= final epilogue: dropout + W_out dot + reductions =================
    {
        float pmacc = 0.0f, pvacc = 0.0f;
        const f32x4* wmp = (const f32x4*)(cbuf + 384);
        const float* bp  = cbuf + 256 + g * 32;
#pragma unroll
        for (int t = 0; t < 8; ++t) {
            f32x4 d4 = md[t];
            f32x4 w4 = wmp[g * 8 + t];
            f32x4 s4 = wmp[32 + g * 8 + t];
            float m0 = (accm[t][0] + bp[t * 4 + 0]) * d4[0];
            float m1 = (accm[t][1] + bp[t * 4 + 1]) * d4[1];
            float m2 = (accm[t][2] + bp[t * 4 + 2]) * d4[2];
            float m3 = (accm[t][3] + bp[t * 4 + 3]) * d4[3];
            float v0 = accv[t][0] * d4[0] * d4[0] + MIN_VARF;
            float v1 = accv[t][1] * d4[1] * d4[1] + MIN_VARF;
            float v2 = accv[t][2] * d4[2] * d4[2] + MIN_VARF;
            float v3 = accv[t][3] * d4[3] * d4[3] + MIN_VARF;
            pmacc += w4[0] * m0 + w4[1] * m1 + w4[2] * m2 + w4[3] * m3;
            pvacc += s4[0] * v0 + s4[1] * v1 + s4[2] * v2 + s4[3] * v3;
        }
        pmacc += __shfl_xor(pmacc, 16, 64);
        pmacc += __shfl_xor(pmacc, 32, 64);
        pvacc += __shfl_xor(pvacc, 16, 64);
        pvacc += __shfl_xor(pvacc, 32, 64);
        float bout = cbuf[640];
        float p = pmacc + bout;
        if (lane < 16) {
            out[ge] = p;
            out[E_TOT + 2 + ge] = occf;
        }
        float a = fabsf(p);
        float loss = fmaxf(p, 0.0f) - p * occf + __logf(1.0f + __expf(-a));
        float al = fabsf(pvacc);
#pragma unroll
        for (int off = 1; off < 16; off <<= 1) {
            al   += __shfl_xor(al, off, 64);
            loss += __shfl_xor(loss, off, 64);
        }
        if (lane == 0) {
            atomicAdd((float*)(ws + RED_OFF), al);
            atomicAdd((float*)(ws + RED_OFF) + 1, loss);
        }
    }
}

__global__ void interp_finalize(const char* __restrict__ ws, float* __restrict__ out)
{
    if (threadIdx.x == 0) {
        const float inv = 1.0f / (float)E_TOT;
        out[E_TOT]     = ((const float*)(ws + RED_OFF))[0] * inv;
        out[E_TOT + 1] = ((const float*)(ws + RED_OFF))[1] * inv;
    }
}

extern "C" void kernel_launch(void* const* d_in, const int* in_sizes, int n_in,
                              void* d_out, int out_size, void* d_ws, size_t ws_size,
                              hipStream_t stream) {
    (void)in_sizes; (void)n_in; (void)out_size; (void)ws_size;
    const float* pos_source = (const float*)d_in[0];
    const float* pos_target = (const float*)d_in[1];
    const float* latents    = (const float*)d_in[2];
    const float* varr       = (const float*)d_in[3];
    const float* drop_mask  = (const float*)d_in[4];
    const float* W_in       = (const float*)d_in[5];
    const float* b_in       = (const float*)d_in[6];
    const float* W1         = (const float*)d_in[7];
    const float* b1         = (const float*)d_in[8];
    const float* W2         = (const float*)d_in[9];
    const float* b2         = (const float*)d_in[10];
    const float* W_out      = (const float*)d_in[11];
    const float* b_out      = (const float*)d_in[12];
    const int*   row        = (const int*)d_in[13];
    const int*   col        = (const int*)d_in[14];
    const int*   occ        = (const int*)d_in[15];
    float* out = (float*)d_out;
    char*  ws  = (char*)d_ws;

    prep<<<29, 256, 0, stream>>>(W_in, b_in, W1, b1, W2, b2, W_out, b_out, ws);
    interp_main<<<E_TOT / 64, 256, 0, stream>>>(
        pos_source, pos_target, latents, varr, drop_mask,
        row, col, occ, out, ws);
    interp_finalize<<<1, 64, 0, stream>>>(ws, out);
}

// Round 5
// 153.018 us; speedup vs baseline: 8.7970x; 3.0302x over previous
//
#include <hip/hip_runtime.h>
#include <math.h>

#define E_TOT 262144
#define LDIM  128
#define XPB   272            // X row pitch in bytes
#define MIN_VARF 0.001f
#define INV_SQRT2PIF 0.3989422804014327f
#define NBLK  (E_TOT / 64)   // 4096 blocks

typedef _Float16 half8 __attribute__((ext_vector_type(8)));
typedef float    f32x4 __attribute__((ext_vector_type(4)));
typedef float    f32x2 __attribute__((ext_vector_type(2)));
typedef __attribute__((address_space(1))) const unsigned int g32;
typedef __attribute__((address_space(3))) unsigned int l32;

// ---- d_ws byte layout ----
#define BIAS_OFF  256      // 3 layers x 128 f32 (reordered [g*32+t*4+r])
#define WOUT_OFF  1792     // 2 x 128 f32 (W_out row0, W_out row0^2; reordered)
#define BOUT_OFF  2816     // 1 f32
#define PK_L0     4096     // 5 ksteps * 8 tiles * 64 lanes * 16 B = 40960
#define PK_L1     45056    // 4 ksteps * 8192 = 32768
#define PK_L2     77824    // 32768 -> end 110592
#define PART_OFF  110592   // NBLK x float2 per-block partials (al, loss) = 32768 B

__device__ __forceinline__ short h2s(float x) {
    union U { _Float16 h; short s; } u; u.h = (_Float16)x; return u.s;
}

// lean ADF-ReLU: rsq-based sqrt/div, native exp, Winitzki erf (abs err ~1.3e-4)
__device__ __forceinline__ void adf_relu(float& m, float& v) {
    float vv = fmaxf(v, 1e-6f);
    float is = __builtin_amdgcn_rsqf(vv);    // 1/sd
    float sd = vv * is;                      // sqrt(vv)
    float r  = m * is;
    float qq = 0.5f * r * r;                 // u^2, u = r/sqrt(2)
    float sp = sd * __expf(-qq) * INV_SQRT2PIF;   // sd * pdf
    const float A = 0.147f;
    float aq  = A * qq;
    float num = qq * (1.27323954f + aq);     // u^2*(4/pi + a u^2)
    float den = 1.0f + aq;
    float z   = -num * __builtin_amdgcn_rcpf(den);
    float wv  = 1.0f - __expf(z);
    float s   = wv * __builtin_amdgcn_rsqf(fmaxf(wv, 1e-20f));  // sqrt(wv)
    float serf = copysignf(s, m);
    float cdf  = 0.5f + 0.5f * serf;
    float mo = fmaf(m, cdf, sp);
    float vo = fmaf(fmaf(m, m, vv), cdf, fmaf(m, sp, -mo * mo));
    m = mo; v = vo;
}

// Pack W (mean path only) into fragment-linear f16:
// entry (ks*8 + t)*64 + lane holds A[row = 16t + (lane&15)][k = 32ks + 8*(lane>>4) + j]
__global__ void prep(const float* __restrict__ W_in, const float* __restrict__ b_in,
                     const float* __restrict__ W1,   const float* __restrict__ b1,
                     const float* __restrict__ W2,   const float* __restrict__ b2,
                     const float* __restrict__ W_out,const float* __restrict__ b_out,
                     char* __restrict__ ws)
{
    int idx = blockIdx.x * 256 + threadIdx.x;
    if (idx < 6656) {
        const float* W; int Kfull; long dstoff; int entry;
        if (idx < 2560)      { entry = idx;        W = W_in; Kfull = 131; dstoff = PK_L0; }
        else if (idx < 4608) { entry = idx - 2560; W = W1;   Kfull = 128; dstoff = PK_L1; }
        else                 { entry = idx - 4608; W = W2;   Kfull = 128; dstoff = PK_L2; }
        int ks   = entry >> 9;
        int rest = entry & 511;
        int t    = rest >> 6;
        int lane = rest & 63;
        int rowi = t * 16 + (lane & 15);
        int k0   = ks * 32 + (lane >> 4) * 8;
        half8 hv;
#pragma unroll
        for (int j = 0; j < 8; ++j) {
            int k = k0 + j;
            hv[j] = (_Float16)((k < Kfull) ? W[rowi * Kfull + k] : 0.0f);
        }
        *(half8*)(ws + dstoff + (long)entry * 16) = hv;
    } else if (idx < 6656 + 384) {
        int j = idx - 6656; int layer = j >> 7; int pidx = j & 127;
        int gg = pidx >> 5, t = (pidx >> 2) & 7, r = pidx & 3;
        int n = t * 16 + gg * 4 + r;
        const float* b = layer == 0 ? b_in : (layer == 1 ? b1 : b2);
        ((float*)(ws + BIAS_OFF))[layer * 128 + pidx] = b[n];
    } else if (idx < 6656 + 384 + 256) {
        int j = idx - 6656 - 384; int path = j >> 7; int pidx = j & 127;
        int gg = pidx >> 5, t = (pidx >> 2) & 7, r = pidx & 3;
        int n = t * 16 + gg * 4 + r;
        float v = W_out[n];
        if (path) v = v * v;
        ((float*)(ws + WOUT_OFF))[path * 128 + pidx] = v;
    } else if (idx == 6656 + 384 + 256) {
        ((float*)(ws + BOUT_OFF))[0] = b_out[0];
    }
}

__global__ void __launch_bounds__(256, 2)
interp_main(const float* __restrict__ pos_source, const float* __restrict__ pos_target,
            const float* __restrict__ latents,    const float* __restrict__ varr,
            const float* __restrict__ drop_mask,
            const int* __restrict__ row, const int* __restrict__ col, const int* __restrict__ occ,
            float* __restrict__ out, char* __restrict__ ws)
{
    __shared__ __align__(16) char  Wl[40960];
    __shared__ __align__(16) short Xm[64][XPB / 2];
    __shared__ __align__(16) short Xv[64][XPB / 2];
    __shared__ __align__(16) float cbuf[648];
    __shared__ float wred[4][2];

    const int tid  = threadIdx.x;
    const int lane = tid & 63;
    const int w    = tid >> 6;
    const int q    = lane & 15;
    const int g    = lane >> 4;
    const int erow = w * 16 + q;
    const int gbase = blockIdx.x * 64;
    const int ge   = gbase + erow;
    char* xmb = (char*)&Xm[0][0];
    char* xvb = (char*)&Xv[0][0];

    // ---- issue async stage of L0 weights into LDS ----
    {
        const char* src = ws + PK_L0;
        for (int off = w * 1024; off < 40960; off += 4096)
            __builtin_amdgcn_global_load_lds((g32*)(src + off + lane * 16), (l32*)(Wl + off), 16, 0, 0);
    }
    // ---- stage biases / W_out / b_out into LDS (cbuf floats: bias@0, wout@384, bout@640) ----
    for (int i = tid; i < 162; i += 256)
        ((f32x4*)cbuf)[i] = ((const f32x4*)(ws + BIAS_OFF))[i];

    // ---- prefetch: mask (nt) into regs, occ, pos_rel, L0 B-fragments ----
    const int c0 = col[ge];
    const int r0 = row[ge];
    f32x4 md[8];
    {
        const f32x4* dmp = (const f32x4*)drop_mask + (size_t)ge * 32 + g;
#pragma unroll
        for (int t = 0; t < 8; ++t) md[t] = __builtin_nontemporal_load(dmp + t * 4);
    }
    const float occf = (float)occ[r0];
    const float px = pos_target[r0 * 3 + 0] - pos_source[c0 * 3 + 0];
    const float py = pos_target[r0 * 3 + 1] - pos_source[c0 * 3 + 1];
    const float pz = pos_target[r0 * 3 + 2] - pos_source[c0 * 3 + 2];

    half8 bm4[4], bv4[4];
    {
        const float* lm = latents + (long)c0 * LDIM;
        const float* lv = varr    + (long)c0 * LDIM;
#pragma unroll
        for (int ks = 0; ks < 4; ++ks) {
            const f32x4* am4 = (const f32x4*)(lm + ks * 32 + g * 8);
            const f32x4* av4 = (const f32x4*)(lv + ks * 32 + g * 8);
            f32x4 fm0 = am4[0], fm1 = am4[1];
            f32x4 fv0 = av4[0], fv1 = av4[1];
            half8 bm, bv;
#pragma unroll
            for (int j = 0; j < 4; ++j) {
                bm[j] = (_Float16)fm0[j]; bm[j + 4] = (_Float16)fm1[j];
                bv[j] = (_Float16)fv0[j]; bv[j + 4] = (_Float16)fv1[j];
            }
            bm4[ks] = bm; bv4[ks] = bv;
        }
    }

    f32x4 accm[8], accv[8];
    const f32x4 zz = {0.0f, 0.0f, 0.0f, 0.0f};
#pragma unroll
    for (int t = 0; t < 8; ++t) { accm[t] = zz; accv[t] = zz; }

    asm volatile("s_waitcnt vmcnt(0)" ::: "memory");
    __syncthreads();

    // ================= layer 0: B from regs, A from LDS =================
    {
#pragma unroll
        for (int ks = 0; ks < 4; ++ks) {
            const char* pmk = Wl + ks * 8192 + lane * 16;
            half8 bm = bm4[ks], bv = bv4[ks];
#pragma unroll
            for (int t = 0; t < 8; ++t) {
                half8 am = *(const half8*)(pmk + t * 1024);
                half8 av = am * am;
                accm[t] = __builtin_amdgcn_mfma_f32_16x16x32_f16(am, bm, accm[t], 0, 0, 0);
                accv[t] = __builtin_amdgcn_mfma_f32_16x16x32_f16(av, bv, accv[t], 0, 0, 0);
            }
        }
        half8 bpos = {(_Float16)0.f, (_Float16)0.f, (_Float16)0.f, (_Float16)0.f,
                      (_Float16)0.f, (_Float16)0.f, (_Float16)0.f, (_Float16)0.f};
        if (g == 0) { bpos[0] = (_Float16)px; bpos[1] = (_Float16)py; bpos[2] = (_Float16)pz; }
        const char* pmk = Wl + 4 * 8192 + lane * 16;
#pragma unroll
        for (int t = 0; t < 8; ++t) {
            half8 am = *(const half8*)(pmk + t * 1024);
            half8 av = am * am;
            accm[t] = __builtin_amdgcn_mfma_f32_16x16x32_f16(am, bpos, accm[t], 0, 0, 0);
            accv[t] = __builtin_amdgcn_mfma_f32_16x16x32_f16(av, bpos, accv[t], 0, 0, 0);
        }
    }

    // all waves done reading W_L0; kick L1 staging, then do L0 epilogue under it
    __syncthreads();
    {
        const char* src = ws + PK_L1;
        for (int off = w * 1024; off < 32768; off += 4096)
            __builtin_amdgcn_global_load_lds((g32*)(src + off + lane * 16), (l32*)(Wl + off), 16, 0, 0);
    }
    {
        const float* bp = cbuf + g * 32;
#pragma unroll
        for (int t = 0; t < 8; ++t) {
            float m0 = accm[t][0] + bp[t * 4 + 0], m1 = accm[t][1] + bp[t * 4 + 1];
            float m2 = accm[t][2] + bp[t * 4 + 2], m3 = accm[t][3] + bp[t * 4 + 3];
            float v0 = accv[t][0], v1 = accv[t][1], v2 = accv[t][2], v3 = accv[t][3];
            adf_relu(m0, v0); adf_relu(m1, v1); adf_relu(m2, v2); adf_relu(m3, v3);
            short4 sm; sm.x = h2s(m0); sm.y = h2s(m1); sm.z = h2s(m2); sm.w = h2s(m3);
            short4 sv; sv.x = h2s(v0); sv.y = h2s(v1); sv.z = h2s(v2); sv.w = h2s(v3);
            *(short4*)(xmb + erow * XPB + t * 32 + g * 8) = sm;
            *(short4*)(xvb + erow * XPB + t * 32 + g * 8) = sv;
        }
    }
    asm volatile("s_waitcnt vmcnt(0)" ::: "memory");
    __syncthreads();

    // ================= layer 1: B from X LDS, A from W LDS =================
#pragma unroll
    for (int t = 0; t < 8; ++t) { accm[t] = zz; accv[t] = zz; }
#pragma unroll
    for (int ks = 0; ks < 4; ++ks) {
        half8 bm = *(const half8*)(xmb + erow * XPB + ks * 64 + g * 16);
        half8 bv = *(const half8*)(xvb + erow * XPB + ks * 64 + g * 16);
        const char* pmk = Wl + ks * 8192 + lane * 16;
#pragma unroll
        for (int t = 0; t < 8; ++t) {
            half8 am = *(const half8*)(pmk + t * 1024);
            half8 av = am * am;
            accm[t] = __builtin_amdgcn_mfma_f32_16x16x32_f16(am, bm, accm[t], 0, 0, 0);
            accv[t] = __builtin_amdgcn_mfma_f32_16x16x32_f16(av, bv, accv[t], 0, 0, 0);
        }
    }

    __syncthreads();
    {
        const char* src = ws + PK_L2;
        for (int off = w * 1024; off < 32768; off += 4096)
            __builtin_amdgcn_global_load_lds((g32*)(src + off + lane * 16), (l32*)(Wl + off), 16, 0, 0);
    }
    {
        const float* bp = cbuf + 128 + g * 32;
#pragma unroll
        for (int t = 0; t < 8; ++t) {
            float m0 = accm[t][0] + bp[t * 4 + 0], m1 = accm[t][1] + bp[t * 4 + 1];
            float m2 = accm[t][2] + bp[t * 4 + 2], m3 = accm[t][3] + bp[t * 4 + 3];
            float v0 = accv[t][0], v1 = accv[t][1], v2 = accv[t][2], v3 = accv[t][3];
            adf_relu(m0, v0); adf_relu(m1, v1); adf_relu(m2, v2); adf_relu(m3, v3);
            short4 sm; sm.x = h2s(m0); sm.y = h2s(m1); sm.z = h2s(m2); sm.w = h2s(m3);
            short4 sv; sv.x = h2s(v0); sv.y = h2s(v1); sv.z = h2s(v2); sv.w = h2s(v3);
            *(short4*)(xmb + erow * XPB + t * 32 + g * 8) = sm;
            *(short4*)(xvb + erow * XPB + t * 32 + g * 8) = sv;
        }
    }
    asm volatile("s_waitcnt vmcnt(0)" ::: "memory");
    __syncthreads();

    // ================= layer 2 =================
#pragma unroll
    for (int t = 0; t < 8; ++t) { accm[t] = zz; accv[t] = zz; }
#pragma unroll
    for (int ks = 0; ks < 4; ++ks) {
        half8 bm = *(const half8*)(xmb + erow * XPB + ks * 64 + g * 16);
        half8 bv = *(const half8*)(xvb + erow * XPB + ks * 64 + g * 16);
        const char* pmk = Wl + ks * 8192 + lane * 16;
#pragma unroll
        for (int t = 0; t < 8; ++t) {
            half8 am = *(const half8*)(pmk + t * 1024);
            half8 av = am * am;
            accm[t] = __builtin_amdgcn_mfma_f32_16x16x32_f16(am, bm, accm[t], 0, 0, 0);
            accv[t] = __builtin_amdgcn_mfma_f32_16x16x32_f16(av, bv, accv[t], 0, 0, 0);
        }
    }

    // ================= final epilogue: dropout + W_out dot + reductions =================
    {
        float pmacc = 0.0f, pvacc = 0.0f;
        const f32x4* wmp = (const f32x4*)(cbuf + 384);
        const float* bp  = cbuf + 256 + g * 32;
#pragma unroll
        for (int t = 0; t < 8; ++t) {
            f32x4 d4 = md[t];
            f32x4 w4 = wmp[g * 8 + t];
            f32x4 s4 = wmp[32 + g * 8 + t];
            float m0 = (accm[t][0] + bp[t * 4 + 0]) * d4[0];
            float m1 = (accm[t][1] + bp[t * 4 + 1]) * d4[1];
            float m2 = (accm[t][2] + bp[t * 4 + 2]) * d4[2];
            float m3 = (accm[t][3] + bp[t * 4 + 3]) * d4[3];
            float v0 = accv[t][0] * d4[0] * d4[0] + MIN_VARF;
            float v1 = accv[t][1] * d4[1] * d4[1] + MIN_VARF;
            float v2 = accv[t][2] * d4[2] * d4[2] + MIN_VARF;
            float v3 = accv[t][3] * d4[3] * d4[3] + MIN_VARF;
            pmacc += w4[0] * m0 + w4[1] * m1 + w4[2] * m2 + w4[3] * m3;
            pvacc += s4[0] * v0 + s4[1] * v1 + s4[2] * v2 + s4[3] * v3;
        }
        pmacc += __shfl_xor(pmacc, 16, 64);
        pmacc += __shfl_xor(pmacc, 32, 64);
        pvacc += __shfl_xor(pvacc, 16, 64);
        pvacc += __shfl_xor(pvacc, 32, 64);
        float bout = cbuf[640];
        float p = pmacc + bout;
        if (lane < 16) {
            out[ge] = p;
            out[E_TOT + 2 + ge] = occf;
        }
        float a = fabsf(p);
        float loss = fmaxf(p, 0.0f) - p * occf + __logf(1.0f + __expf(-a));
        float al = fabsf(pvacc);
#pragma unroll
        for (int off = 1; off < 16; off <<= 1) {
            al   += __shfl_xor(al, off, 64);
            loss += __shfl_xor(loss, off, 64);
        }
        if (lane == 0) { wred[w][0] = al; wred[w][1] = loss; }
    }
    __syncthreads();
    if (tid == 0) {
        f32x2 s;
        s[0] = wred[0][0] + wred[1][0] + wred[2][0] + wred[3][0];
        s[1] = wred[0][1] + wred[1][1] + wred[2][1] + wred[3][1];
        *((f32x2*)(ws + PART_OFF) + blockIdx.x) = s;   // plain store, no atomics
    }
}

__global__ void __launch_bounds__(256)
interp_finalize(const char* __restrict__ ws, float* __restrict__ out)
{
    __shared__ float sal[4], sls[4];
    const int tid  = threadIdx.x;
    const int lane = tid & 63;
    const int w    = tid >> 6;
    float al = 0.0f, ls = 0.0f;
    const f32x2* part = (const f32x2*)(ws + PART_OFF);
    for (int i = tid; i < NBLK; i += 256) {
        f32x2 p = part[i];
        al += p[0]; ls += p[1];
    }
#pragma unroll
    for (int off = 1; off < 64; off <<= 1) {
        al += __shfl_xor(al, off, 64);
        ls += __shfl_xor(ls, off, 64);
    }
    if (lane == 0) { sal[w] = al; sls[w] = ls; }
    __syncthreads();
    if (tid == 0) {
        const float inv = 1.0f / (float)E_TOT;
        out[E_TOT]     = (sal[0] + sal[1] + sal[2] + sal[3]) * inv;
        out[E_TOT + 1] = (sls[0] + sls[1] + sls[2] + sls[3]) * inv;
    }
}

extern "C" void kernel_launch(void* const* d_in, const int* in_sizes, int n_in,
                              void* d_out, int out_size, void* d_ws, size_t ws_size,
                              hipStream_t stream) {
    (void)in_sizes; (void)n_in; (void)out_size; (void)ws_size;
    const float* pos_source = (const float*)d_in[0];
    const float* pos_target = (const float*)d_in[1];
    const float* latents    = (const float*)d_in[2];
    const float* varr       = (const float*)d_in[3];
    const float* drop_mask  = (const float*)d_in[4];
    const float* W_in       = (const float*)d_in[5];
    const float* b_in       = (const float*)d_in[6];
    const float* W1         = (const float*)d_in[7];
    const float* b1         = (const float*)d_in[8];
    const float* W2         = (const float*)d_in[9];
    const float* b2         = (const float*)d_in[10];
    const float* W_out      = (const float*)d_in[11];
    const float* b_out      = (const float*)d_in[12];
    const int*   row        = (const int*)d_in[13];
    const int*   col        = (const int*)d_in[14];
    const int*   occ        = (const int*)d_in[15];
    float* out = (float*)d_out;
    char*  ws  = (char*)d_ws;

    prep<<<29, 256, 0, stream>>>(W_in, b_in, W1, b1, W2, b2, W_out, b_out, ws);
    interp_main<<<NBLK, 256, 0, stream>>>(
        pos_source, pos_target, latents, varr, drop_mask,
        row, col, occ, out, ws);
    interp_finalize<<<1, 256, 0, stream>>>(ws, out);
}